// Round 6
// baseline (309.137 us; speedup 1.0000x reference)
//
#include <hip/hip_runtime.h>

typedef short bf16x8 __attribute__((ext_vector_type(8)));
typedef float f32x4 __attribute__((ext_vector_type(4)));
typedef unsigned short u16;
typedef u16 ushort8v __attribute__((ext_vector_type(8)));

// ---- constants ----
#define VOCAB 100000
#define EMB 300
#define SEQ 40
#define BATCH 8192
#define COUT 210
#define NBLK 5
#define KPOOL 38
#define DH 35
#define NCLS 35
#define PCOL 320            // padded w2v row: 300 real + 20 zero (16B-aligned rows)
#define KDIM 960            // 3*320
#define NUSE 192            // only channels 0..189 feed the pool
#define BM 64
#define NGR 120             // KDIM/8 granules

__device__ __forceinline__ u16 f2bf(float f) {
  unsigned u = __float_as_uint(f);
  unsigned r = 0x7FFFu + ((u >> 16) & 1u);
  return (u16)((u + r) >> 16);
}

__device__ __forceinline__ void gload_lds16(void* lds, const void* g) {
  __builtin_amdgcn_global_load_lds(
      (const __attribute__((address_space(1))) void*)g,
      (__attribute__((address_space(3))) void*)lds, 16, 0, 0);
}

// ---- kernel 1: w2v f32 [VOCAB][300] -> W bf16 [VOCAB+1][320]; row VOCAB = zeros ----
__global__ __launch_bounds__(256) void k_prepW(const float* __restrict__ w2v,
                                               u16* __restrict__ W) {
  int id = blockIdx.x * 256 + threadIdx.x;          // (VOCAB+1)*40 chunks of 8
  if (id >= (VOCAB + 1) * 40) return;
  int v = id / 40, e8 = id - v * 40;
  int e = e8 * 8;
  float vals[8] = {0.f, 0.f, 0.f, 0.f, 0.f, 0.f, 0.f, 0.f};
  if (v < VOCAB) {
    const float* src = w2v + (size_t)v * EMB + e;
    if (e <= 292) {
      float4 f0 = *(const float4*)src;
      float4 f1 = *(const float4*)(src + 4);
      vals[0] = f0.x; vals[1] = f0.y; vals[2] = f0.z; vals[3] = f0.w;
      vals[4] = f1.x; vals[5] = f1.y; vals[6] = f1.z; vals[7] = f1.w;
    } else if (e == 296) {
      float4 f0 = *(const float4*)src;               // 296..299
      vals[0] = f0.x; vals[1] = f0.y; vals[2] = f0.z; vals[3] = f0.w;
    }
  }
  ushort8v o;
#pragma unroll
  for (int j = 0; j < 8; ++j) o[j] = f2bf(vals[j]);
  *(ushort8v*)(W + (size_t)v * PCOL + e) = o;
}

// ---- kernel 2: conv_w [3][300][210] -> Btn bf16 [120 gran][192 col][8] (zero padded) ----
__global__ __launch_bounds__(256) void k_prepB(const float* __restrict__ convw,
                                               u16* __restrict__ Btn) {
  int id = blockIdx.x * 256 + threadIdx.x;          // 120*192 = 23040
  if (id >= NGR * NUSE) return;
  int gg = id / NUSE, col = id - gg * NUSE;
  ushort8v o;
#pragma unroll
  for (int j = 0; j < 8; ++j) {
    int k = gg * 8 + j;
    int kh = (k >= 640) ? 2 : (k >= 320 ? 1 : 0);
    int e = k - kh * PCOL;
    float v = (e < EMB) ? convw[(kh * EMB + e) * COUT + col] : 0.f;
    o[j] = f2bf(v);
  }
  *(ushort8v*)(Btn + (size_t)id * 8) = o;
}

// ---- kernel 3: fused gather + conv GEMM (M=327680, N=192, K=960) + bias/relu/pool-max ----
// 256 threads = 4 waves (1M x 4N), wave tile 64x48, BM=64, BK=32, 30 K-tiles.
// 8 LDS A-bufs (4KB each), A staged 4 tiles ahead via per-lane global_load_lds gather
// from W; B direct global->VGPR, 4 rotating sets, 2-3 tiles ahead. ONE barrier per
// 2 tiles; counted vmcnt(2) ledger: each superstep issues [6xB, 2xA]; leaving the 2
// newest A-stages outstanding retires everything >= 2 supersteps old.
__global__ __launch_bounds__(256, 4) void k_conv_gemm(const u16* __restrict__ Wb,
                                                      const u16* __restrict__ Btn,
                                                      const int* __restrict__ x,
                                                      const float* __restrict__ convb,
                                                      float* __restrict__ maxc) {
  __shared__ __align__(16) char smem[32768];        // 8 x 4KB A-bufs; epilogue act[32][194]
  float* act = (float*)smem;

  const int tid = threadIdx.x;
  const int lane = tid & 63;
  const int wc = tid >> 6;                          // wave = N-slot 0..3
  const int l15 = lane & 15, l4 = lane >> 4;
  const int m0 = blockIdx.x * BM;

  // --- A staging setup: thread stages chunk (granule ag=tid>>6, row ar=tid&63) ---
  const int ag = tid >> 6, ar = tid & 63;
  unsigned offm1, off0, offp1;                      // element offsets into W for 3 tokens
  {
    const int m = m0 + ar;
    const int b = m / SEQ, s = m - b * SEQ;
    const unsigned im1 = (s == 0)       ? VOCAB : (unsigned)x[b * SEQ + s - 1];
    const unsigned i0  =                           (unsigned)x[b * SEQ + s];
    const unsigned ip1 = (s == SEQ - 1) ? VOCAB : (unsigned)x[b * SEQ + s + 1];
    offm1 = im1 * PCOL; off0 = i0 * PCOL; offp1 = ip1 * PCOL;
  }

  // --- B direct-load setup: frag base for (granule l4, col wc*48+l15) ---
  const u16* pbB = Btn + (size_t)((l4 * NUSE) + wc * 48 + l15) * 8;

  const int aoff = (l4 * 64 + l15) * 16;            // + fm*256 within a 4KB buf

  f32x4 acc[4][3];
  const f32x4 zero = {0.f, 0.f, 0.f, 0.f};
#pragma unroll
  for (int i = 0; i < 4; ++i)
#pragma unroll
    for (int j = 0; j < 3; ++j) acc[i][j] = zero;

  bf16x8 bs0[3], bs1[3], bs2[3], bs3[3];            // 4 rotating B sets (12 VGPR each)

#define STAGEA(T, BUF)                                                         \
  {                                                                            \
    const int koff_ = (T) * 32 + ag * 8;                                       \
    unsigned off_ = (koff_ < 320) ? (offm1 + koff_)                            \
                  : (koff_ < 640) ? (off0 + (koff_ - 320))                     \
                                  : (offp1 + (koff_ - 640));                   \
    gload_lds16(smem + (BUF) * 4096 + tid * 16, Wb + off_);                    \
  }

#define LOADB(SET, T)                                                          \
  {                                                                            \
    const u16* p_ = pbB + (size_t)(T) * 6144;                                  \
    SET[0] = *(const bf16x8*)(p_);                                             \
    SET[1] = *(const bf16x8*)(p_ + 128);                                       \
    SET[2] = *(const bf16x8*)(p_ + 256);                                       \
  }

#define COMP(BUF, SET)                                                         \
  {                                                                            \
    const char* A_ = smem + (BUF) * 4096;                                      \
    bf16x8 a0_ = *(const bf16x8*)(A_ + aoff);                                  \
    bf16x8 a1_ = *(const bf16x8*)(A_ + aoff + 256);                            \
    bf16x8 a2_ = *(const bf16x8*)(A_ + aoff + 512);                            \
    bf16x8 a3_ = *(const bf16x8*)(A_ + aoff + 768);                            \
    __builtin_amdgcn_s_setprio(1);                                             \
    _Pragma("unroll")                                                          \
    for (int fn_ = 0; fn_ < 3; ++fn_) {                                        \
      acc[0][fn_] = __builtin_amdgcn_mfma_f32_16x16x32_bf16(a0_, SET[fn_], acc[0][fn_], 0, 0, 0); \
      acc[1][fn_] = __builtin_amdgcn_mfma_f32_16x16x32_bf16(a1_, SET[fn_], acc[1][fn_], 0, 0, 0); \
      acc[2][fn_] = __builtin_amdgcn_mfma_f32_16x16x32_bf16(a2_, SET[fn_], acc[2][fn_], 0, 0, 0); \
      acc[3][fn_] = __builtin_amdgcn_mfma_f32_16x16x32_bf16(a3_, SET[fn_], acc[3][fn_], 0, 0, 0); \
    }                                                                          \
    __builtin_amdgcn_s_setprio(0);                                             \
  }

#define WAITV(N) asm volatile("s_waitcnt vmcnt(" #N ")" ::: "memory")
#define BARRIER                                                                \
  __builtin_amdgcn_sched_barrier(0);                                           \
  __builtin_amdgcn_s_barrier();                                                \
  __builtin_amdgcn_sched_barrier(0)
#define FENCE __builtin_amdgcn_sched_barrier(0)

  // prologue: queue = [B0x3, B1x3, A0, A1, A2, A3]
  LOADB(bs0, 0); LOADB(bs1, 1);
  STAGEA(0, 0); STAGEA(1, 1); STAGEA(2, 2); STAGEA(3, 3);

#pragma unroll 1
  for (int i = 0; i < 3; ++i) {                     // tiles 8i .. 8i+7
    const int t0 = i * 8;
    WAITV(2); BARRIER;
    LOADB(bs2, t0 + 2); LOADB(bs3, t0 + 3); STAGEA(t0 + 4, 4); STAGEA(t0 + 5, 5);
    FENCE;
    COMP(0, bs0); COMP(1, bs1);                     // tiles t0, t0+1

    WAITV(2); BARRIER;
    LOADB(bs0, t0 + 4); LOADB(bs1, t0 + 5); STAGEA(t0 + 6, 6); STAGEA(t0 + 7, 7);
    FENCE;
    COMP(2, bs2); COMP(3, bs3);                     // tiles t0+2, t0+3

    WAITV(2); BARRIER;
    LOADB(bs2, t0 + 6); LOADB(bs3, t0 + 7); STAGEA(t0 + 8, 0); STAGEA(t0 + 9, 1);
    FENCE;
    COMP(4, bs0); COMP(5, bs1);                     // tiles t0+4, t0+5

    WAITV(2); BARRIER;
    LOADB(bs0, t0 + 8); LOADB(bs1, t0 + 9); STAGEA(t0 + 10, 2); STAGEA(t0 + 11, 3);
    FENCE;
    COMP(6, bs2); COMP(7, bs3);                     // tiles t0+6, t0+7
  }

  // tail: tiles 24..29
  WAITV(2); BARRIER;
  LOADB(bs2, 26); LOADB(bs3, 27); STAGEA(28, 4); STAGEA(29, 5);
  FENCE;
  COMP(0, bs0); COMP(1, bs1);                       // 24, 25

  WAITV(2); BARRIER;
  LOADB(bs0, 28); LOADB(bs1, 29);
  FENCE;
  COMP(2, bs2); COMP(3, bs3);                       // 26, 27

  WAITV(0); BARRIER;
  COMP(4, bs0); COMP(5, bs1);                       // 28, 29

#undef STAGEA
#undef LOADB
#undef COMP
#undef WAITV
#undef BARRIER
#undef FENCE

  __syncthreads();                                  // A-bufs -> act reuse

  // epilogue: 2 chunks of 32 rows; bias+relu -> LDS -> per-(row,group) max over 38
  // channels. Fully unrolled: every acc[] index compile-time (rule #20).
#pragma unroll
  for (int ch = 0; ch < 2; ++ch) {
    const int fbase = ch * 2;
#pragma unroll
    for (int fi = 0; fi < 2; ++fi) {
#pragma unroll
      for (int fn = 0; fn < 3; ++fn) {
        const int col = wc * 48 + fn * 16 + l15;    // < 192 < 210
        const float bias = convb[col];
#pragma unroll
        for (int rg = 0; rg < 4; ++rg) {
          const int rloc = fi * 16 + l4 * 4 + rg;   // 0..31 within chunk
          float vv = acc[fbase + fi][fn][rg] + bias;
          act[rloc * 194 + col] = fmaxf(vv, 0.f);
        }
      }
    }
    __syncthreads();
    if (tid < 160) {                                // 32 rows x 5 groups
      const int rl = tid / 5, gq = tid - rl * 5;
      const float* ap = act + rl * 194 + gq * KPOOL;
      float mx = 0.f;                               // relu => values >= 0
#pragma unroll
      for (int i = 0; i < KPOOL; ++i) mx = fmaxf(mx, ap[i]);
      const int m = m0 + ch * 32 + rl;
      const int bb = m / SEQ, ss = m - bb * SEQ;
      maxc[(bb * NBLK + gq) * SEQ + ss] = mx;       // unmasked max; mask applied in k_dense
    }
    __syncthreads();
  }
}

// ---- kernel 4: region-masked dense (120->35) + out (35->35) ----
__global__ __launch_bounds__(256) void k_dense(const float* __restrict__ maxc,
                                               const int* __restrict__ pos,
                                               const float* __restrict__ dw,
                                               const float* __restrict__ db,
                                               const float* __restrict__ ow,
                                               const float* __restrict__ ob,
                                               float* __restrict__ out) {
  __shared__ float dwL[120 * 36];
  __shared__ float owL[35 * 36];
  __shared__ float hL[64 * 36];
  __shared__ float mxL[64 * 40];
  const int tid = threadIdx.x;
  const int r0 = blockIdx.x * 64;                    // 640 blocks x 64 rows
  for (int i = tid; i < 120 * 35; i += 256) { int j = i / 35, d = i - j * 35; dwL[j * 36 + d] = dw[i]; }
  for (int i = tid; i < 35 * 35; i += 256)  { int j = i / 35, d = i - j * 35; owL[j * 36 + d] = ow[i]; }
  for (int i = tid; i < 64 * 40; i += 256)  mxL[i] = maxc[(size_t)r0 * 40 + i];
  __syncthreads();
  for (int t = tid; t < 64 * 35; t += 256) {
    const int row = t / 35, d = t - row * 35;
    const int rg = r0 + row;
    const int b = rg / NBLK;
    const int p0 = pos[b * 2], p1 = pos[b * 2 + 1];
    int e1 = min(p0, p1), e2 = max(p0, p1);
    if (e1 == 0) { e1 = 1; e2 += 1; }
    float a = db[d];
#pragma unroll
    for (int s = 0; s < SEQ; ++s) {
      const int k = (s >= e1) + (s >= e2);           // region of position s
      a += mxL[row * 40 + s] * dwL[(k * SEQ + s) * 36 + d];
    }
    hL[row * 36 + d] = a;
  }
  __syncthreads();
  for (int t = tid; t < 64 * 35; t += 256) {
    const int row = t / 35, c = t - row * 35;
    float a = ob[c];
#pragma unroll
    for (int d = 0; d < DH; ++d) a += hL[row * 36 + d] * owL[d * 36 + c];
    out[(size_t)(r0 + row) * NCLS + c] = a;
  }
}

extern "C" void kernel_launch(void* const* d_in, const int* in_sizes, int n_in,
                              void* d_out, int out_size, void* d_ws, size_t ws_size,
                              hipStream_t stream) {
  const int*   x     = (const int*)d_in[0];
  const int*   pos   = (const int*)d_in[1];
  const float* w2v   = (const float*)d_in[2];
  const float* convw = (const float*)d_in[3];
  const float* convb = (const float*)d_in[4];
  const float* dw    = (const float*)d_in[5];
  const float* db    = (const float*)d_in[6];
  const float* ow    = (const float*)d_in[7];
  const float* ob    = (const float*)d_in[8];
  float* out = (float*)d_out;

  char* ws = (char*)d_ws;
  u16* W    = (u16*)ws;                               // (100001)*320*2 = 64,000,640 B
  u16* Btn  = (u16*)(ws + 64000640);                  // 120*192*8*2   =    368,640 B
  float* maxc = (float*)(ws + 64000640 + 368640);     // 40960*40*4    =  6,553,600 B

  k_prepW<<<15626, 256, 0, stream>>>(w2v, W);         // (100001*40+255)/256
  k_prepB<<<90, 256, 0, stream>>>(convw, Btn);        // 23040/256
  k_conv_gemm<<<5120, 256, 0, stream>>>(W, Btn, x, convb, maxc);  // 327680/64
  k_dense<<<640, 256, 0, stream>>>(maxc, pos, dw, db, ow, ob, out);
}

// Round 7
// 182.291 us; speedup vs baseline: 1.6958x; 1.6958x over previous
//
#include <hip/hip_runtime.h>

typedef short bf16x8 __attribute__((ext_vector_type(8)));
typedef float f32x4 __attribute__((ext_vector_type(4)));
typedef unsigned short u16;
typedef u16 ushort8v __attribute__((ext_vector_type(8)));

// ---- constants ----
#define VOCAB 100000
#define EMB 300
#define SEQ 40
#define BATCH 8192
#define COUT 210
#define NBLK 5
#define KPOOL 38
#define DH 35
#define NCLS 35
#define PCOL 320            // padded w2v row: 300 real + 20 zero (16B-aligned rows)
#define KDIM 960            // 3*320
#define NUSE 192            // only channels 0..189 feed the pool
#define BM 80               // 2 batches per block
#define EROWS 84            // 2 x 42 padded embedding rows resident in LDS
#define NGR 120             // KDIM/8 granules

__device__ __forceinline__ u16 f2bf(float f) {
  unsigned u = __float_as_uint(f);
  unsigned r = 0x7FFFu + ((u >> 16) & 1u);
  return (u16)((u + r) >> 16);
}

__device__ __forceinline__ void gload_lds16(void* lds, const void* g) {
  __builtin_amdgcn_global_load_lds(
      (const __attribute__((address_space(1))) void*)g,
      (__attribute__((address_space(3))) void*)lds, 16, 0, 0);
}

// ---- kernel 1: w2v f32 [VOCAB][300] -> W bf16 [VOCAB+1][320]; row VOCAB = zeros ----
__global__ __launch_bounds__(256) void k_prepW(const float* __restrict__ w2v,
                                               u16* __restrict__ W) {
  int id = blockIdx.x * 256 + threadIdx.x;          // (VOCAB+1)*40 chunks of 8
  if (id >= (VOCAB + 1) * 40) return;
  int v = id / 40, e8 = id - v * 40;
  int e = e8 * 8;
  float vals[8] = {0.f, 0.f, 0.f, 0.f, 0.f, 0.f, 0.f, 0.f};
  if (v < VOCAB) {
    const float* src = w2v + (size_t)v * EMB + e;
    if (e <= 292) {
      float4 f0 = *(const float4*)src;
      float4 f1 = *(const float4*)(src + 4);
      vals[0] = f0.x; vals[1] = f0.y; vals[2] = f0.z; vals[3] = f0.w;
      vals[4] = f1.x; vals[5] = f1.y; vals[6] = f1.z; vals[7] = f1.w;
    } else if (e == 296) {
      float4 f0 = *(const float4*)src;               // 296..299
      vals[0] = f0.x; vals[1] = f0.y; vals[2] = f0.z; vals[3] = f0.w;
    }
  }
  ushort8v o;
#pragma unroll
  for (int j = 0; j < 8; ++j) o[j] = f2bf(vals[j]);
  *(ushort8v*)(W + (size_t)v * PCOL + e) = o;
}

// ---- kernel 2: conv_w [3][300][210] -> Btn bf16 [120 gran][192 col][8] (zero padded) ----
__global__ __launch_bounds__(256) void k_prepB(const float* __restrict__ convw,
                                               u16* __restrict__ Btn) {
  int id = blockIdx.x * 256 + threadIdx.x;          // 120*192 = 23040
  if (id >= NGR * NUSE) return;
  int gg = id / NUSE, col = id - gg * NUSE;
  ushort8v o;
#pragma unroll
  for (int j = 0; j < 8; ++j) {
    int k = gg * 8 + j;
    int kh = (k >= 640) ? 2 : (k >= 320 ? 1 : 0);
    int e = k - kh * PCOL;
    float v = (e < EMB) ? convw[(kh * EMB + e) * COUT + col] : 0.f;
    o[j] = f2bf(v);
  }
  *(ushort8v*)(Btn + (size_t)id * 8) = o;
}

// ---- kernel 3: fused gather + conv (as 3 shifted K=320 sub-GEMMs) + bias/relu/pool ----
// Block = 2 batches (BM=80 output rows). Prologue: stage the 84 padded embedding rows
// ONCE into LDS (k-major [40 gran][84 row]x16B, gathered per-lane from W). Main loop:
// 30 steps (kh 0..2 x kq 0..9) of pure ds_read + MFMA -- NO barriers, NO staging, NO
// vmcnt asm. A-frag rows shift by kh inside the resident tile (im2col for free).
// 4 waves (1M x 4N), wave tile 80x48: acc[5][3]; B direct global->VGPR, 3 rotating sets.
__global__ __launch_bounds__(256) void k_conv_gemm(const u16* __restrict__ Wb,
                                                   const u16* __restrict__ Btn,
                                                   const int* __restrict__ x,
                                                   const float* __restrict__ convb,
                                                   float* __restrict__ maxc) {
  __shared__ __align__(16) char smem[40 * EROWS * 16];   // 53760 B; epilogue aliases act
  float* act = (float*)smem;                             // [16][194] per chunk

  const int tid = threadIdx.x;
  const int lane = tid & 63;
  const int wc = tid >> 6;                          // wave = N-slot 0..3
  const int l15 = lane & 15, l4 = lane >> 4;
  const int m0 = blockIdx.x * BM;
  const int b0 = blockIdx.x * 2;

  // ---- prologue: gather E-tile [g][prow] : chunk c -> (g=c/84, prow=c%84) ----
  // prow 0..41 = batch b0 (sp=0,41 pads), 42..83 = batch b0+1.
#pragma unroll
  for (int ri = 0; ri < 13; ++ri) {
    const int c = ri * 256 + tid;
    const int g = c / 84;
    const int prow = c - g * 84;
    const int bb = (prow >= 42) ? 1 : 0;
    const int sp = prow - 42 * bb;
    const int tok = (sp == 0 || sp == 41) ? VOCAB : x[(b0 + bb) * SEQ + sp - 1];
    gload_lds16(smem + c * 16, Wb + (size_t)tok * PCOL + g * 8);
  }
  if (tid < 32) {                                   // chunks 3328..3359
    const int c = 3328 + tid;
    const int g = c / 84;
    const int prow = c - g * 84;
    const int bb = (prow >= 42) ? 1 : 0;
    const int sp = prow - 42 * bb;
    const int tok = (sp == 0 || sp == 41) ? VOCAB : x[(b0 + bb) * SEQ + sp - 1];
    gload_lds16(smem + c * 16, Wb + (size_t)tok * PCOL + g * 8);
  }
  __syncthreads();                                  // drains vmcnt -> E-tile resident

  // ---- per-lane A row indices (fold batch-boundary pad jump): prow = m_local + 2*(m_local>=40) ----
  const int rA0 = l15;                              // fm=0: rows 0..15
  const int rA1 = 16 + l15;                         // fm=1
  const int rA2 = 32 + l15 + ((l15 >= 8) ? 2 : 0);  // fm=2 straddles batch boundary
  const int rA3 = 50 + l15;                         // fm=3: 48+l15+2
  const int rA4 = 66 + l15;                         // fm=4: 64+l15+2

  // ---- B setup: frag (granule l4 within tile, col wc*48+l15); tile T at +T*6144 elems ----
  const u16* pbB = Btn + (size_t)((l4 * NUSE) + wc * 48 + l15) * 8;

  f32x4 acc[5][3];
  const f32x4 zero = {0.f, 0.f, 0.f, 0.f};
#pragma unroll
  for (int i = 0; i < 5; ++i)
#pragma unroll
    for (int j = 0; j < 3; ++j) acc[i][j] = zero;

  bf16x8 bs[3][3];                                  // 3 rotating B sets (12 VGPR each)

#define LOADB(SI, T)                                                           \
  {                                                                            \
    const u16* p_ = pbB + (size_t)(T) * 6144;                                  \
    bs[SI][0] = *(const bf16x8*)(p_);                                          \
    bs[SI][1] = *(const bf16x8*)(p_ + 128);                                    \
    bs[SI][2] = *(const bf16x8*)(p_ + 256);                                    \
  }

  LOADB(0, 0)
  LOADB(1, 1)

#pragma unroll
  for (int kh = 0; kh < 3; ++kh) {
#pragma unroll
    for (int kq = 0; kq < 10; ++kq) {
      const int t = kh * 10 + kq;
      if (t + 2 < 30) LOADB((t + 2) % 3, t + 2)
      const char* kb = smem + ((kq * 4 + l4) * EROWS + kh) * 16;
      bf16x8 a0 = *(const bf16x8*)(kb + rA0 * 16);
      bf16x8 a1 = *(const bf16x8*)(kb + rA1 * 16);
      bf16x8 a2 = *(const bf16x8*)(kb + rA2 * 16);
      bf16x8 a3 = *(const bf16x8*)(kb + rA3 * 16);
      bf16x8 a4 = *(const bf16x8*)(kb + rA4 * 16);
      __builtin_amdgcn_s_setprio(1);
#pragma unroll
      for (int fn = 0; fn < 3; ++fn) {
        acc[0][fn] = __builtin_amdgcn_mfma_f32_16x16x32_bf16(a0, bs[t % 3][fn], acc[0][fn], 0, 0, 0);
        acc[1][fn] = __builtin_amdgcn_mfma_f32_16x16x32_bf16(a1, bs[t % 3][fn], acc[1][fn], 0, 0, 0);
        acc[2][fn] = __builtin_amdgcn_mfma_f32_16x16x32_bf16(a2, bs[t % 3][fn], acc[2][fn], 0, 0, 0);
        acc[3][fn] = __builtin_amdgcn_mfma_f32_16x16x32_bf16(a3, bs[t % 3][fn], acc[3][fn], 0, 0, 0);
        acc[4][fn] = __builtin_amdgcn_mfma_f32_16x16x32_bf16(a4, bs[t % 3][fn], acc[4][fn], 0, 0, 0);
      }
      __builtin_amdgcn_s_setprio(0);
    }
  }
#undef LOADB

  __syncthreads();                                  // all E reads done -> act aliasing safe

  // ---- epilogue: 5 chunks of 16 rows (one per fm); bias+relu -> LDS -> channel-group max ----
#pragma unroll
  for (int fm = 0; fm < 5; ++fm) {
#pragma unroll
    for (int fn = 0; fn < 3; ++fn) {
      const int col = wc * 48 + fn * 16 + l15;      // < 192 < 210
      const float bias = convb[col];
#pragma unroll
      for (int rg = 0; rg < 4; ++rg) {
        const int rloc = l4 * 4 + rg;               // 0..15 within chunk
        float vv = acc[fm][fn][rg] + bias;
        act[rloc * 194 + col] = fmaxf(vv, 0.f);
      }
    }
    __syncthreads();
    if (tid < 80) {                                 // 16 rows x 5 groups
      const int rl = tid / 5, gq = tid - rl * 5;
      const float* ap = act + rl * 194 + gq * KPOOL;
      float mx = 0.f;                               // relu => values >= 0
#pragma unroll
      for (int i = 0; i < KPOOL; ++i) mx = fmaxf(mx, ap[i]);
      const int mloc = fm * 16 + rl;
      const int bb = (mloc >= 40) ? 1 : 0;
      const int ss = mloc - 40 * bb;
      maxc[((b0 + bb) * NBLK + gq) * SEQ + ss] = mx; // unmasked max; mask applied in k_dense
    }
    __syncthreads();
  }
}

// ---- kernel 4: region-masked dense (120->35) + out (35->35) ----
__global__ __launch_bounds__(256) void k_dense(const float* __restrict__ maxc,
                                               const int* __restrict__ pos,
                                               const float* __restrict__ dw,
                                               const float* __restrict__ db,
                                               const float* __restrict__ ow,
                                               const float* __restrict__ ob,
                                               float* __restrict__ out) {
  __shared__ float dwL[120 * 36];
  __shared__ float owL[35 * 36];
  __shared__ float hL[64 * 36];
  __shared__ float mxL[64 * 40];
  const int tid = threadIdx.x;
  const int r0 = blockIdx.x * 64;                    // 640 blocks x 64 rows
  for (int i = tid; i < 120 * 35; i += 256) { int j = i / 35, d = i - j * 35; dwL[j * 36 + d] = dw[i]; }
  for (int i = tid; i < 35 * 35; i += 256)  { int j = i / 35, d = i - j * 35; owL[j * 36 + d] = ow[i]; }
  for (int i = tid; i < 64 * 40; i += 256)  mxL[i] = maxc[(size_t)r0 * 40 + i];
  __syncthreads();
  for (int t = tid; t < 64 * 35; t += 256) {
    const int row = t / 35, d = t - row * 35;
    const int rg = r0 + row;
    const int b = rg / NBLK;
    const int p0 = pos[b * 2], p1 = pos[b * 2 + 1];
    int e1 = min(p0, p1), e2 = max(p0, p1);
    if (e1 == 0) { e1 = 1; e2 += 1; }
    float a = db[d];
#pragma unroll
    for (int s = 0; s < SEQ; ++s) {
      const int k = (s >= e1) + (s >= e2);           // region of position s
      a += mxL[row * 40 + s] * dwL[(k * SEQ + s) * 36 + d];
    }
    hL[row * 36 + d] = a;
  }
  __syncthreads();
  for (int t = tid; t < 64 * 35; t += 256) {
    const int row = t / 35, c = t - row * 35;
    float a = ob[c];
#pragma unroll
    for (int d = 0; d < DH; ++d) a += hL[row * 36 + d] * owL[d * 36 + c];
    out[(size_t)(r0 + row) * NCLS + c] = a;
  }
}

extern "C" void kernel_launch(void* const* d_in, const int* in_sizes, int n_in,
                              void* d_out, int out_size, void* d_ws, size_t ws_size,
                              hipStream_t stream) {
  const int*   x     = (const int*)d_in[0];
  const int*   pos   = (const int*)d_in[1];
  const float* w2v   = (const float*)d_in[2];
  const float* convw = (const float*)d_in[3];
  const float* convb = (const float*)d_in[4];
  const float* dw    = (const float*)d_in[5];
  const float* db    = (const float*)d_in[6];
  const float* ow    = (const float*)d_in[7];
  const float* ob    = (const float*)d_in[8];
  float* out = (float*)d_out;

  char* ws = (char*)d_ws;
  u16* W    = (u16*)ws;                               // (100001)*320*2 = 64,000,640 B
  u16* Btn  = (u16*)(ws + 64000640);                  // 120*192*8*2   =    368,640 B
  float* maxc = (float*)(ws + 64000640 + 368640);     // 40960*40*4    =  6,553,600 B

  k_prepW<<<15626, 256, 0, stream>>>(w2v, W);         // (100001*40+255)/256
  k_prepB<<<90, 256, 0, stream>>>(convw, Btn);        // 23040/256
  k_conv_gemm<<<4096, 256, 0, stream>>>(W, Btn, x, convb, maxc);  // 327680/80
  k_dense<<<640, 256, 0, stream>>>(maxc, pos, dw, db, ow, ob, out);
}